// Round 1
// baseline (180.969 us; speedup 1.0000x reference)
//
#include <hip/hip_runtime.h>
#include <hip/hip_bf16.h>
#include <math.h>

// Problem constants
#define BB   32
#define HN   12
#define N1   256
#define N2   320
#define SS   256
#define BH   (BB*HN)            // 384
#define ROWS (BH*N1)            // 98304 rows per tensor
#define N4PT ((BH*N1*N2)/4)     // float4 count per tensor = 7,864,320

// ---------------- Kernel 1: row max over N2 for both tensors ----------------
// one wave (64 lanes) per row; 320 = 64*5 strided loads, coalesced.
__global__ __launch_bounds__(256) void k_rowmax(
    const float* __restrict__ rgb, const float* __restrict__ tir,
    float* __restrict__ mxr, float* __restrict__ mxt)
{
    int wid  = (blockIdx.x * 256 + threadIdx.x) >> 6;   // global wave id
    int lane = threadIdx.x & 63;
    int isTir = wid >= ROWS;
    int row  = isTir ? wid - ROWS : wid;
    const float* p = (isTir ? tir : rgb) + (size_t)row * N2;
    float m = -INFINITY;
#pragma unroll
    for (int k = 0; k < 5; ++k) m = fmaxf(m, p[lane + k * 64]);
#pragma unroll
    for (int off = 32; off; off >>= 1) m = fmaxf(m, __shfl_xor(m, off));
    if (lane == 0) (isTir ? mxt : mxr)[row] = m;
}

// ---------------- Kernel 2: scatter -> LayerNorm -> MLP -> gather gates -----
// one block (256 threads) per (b,h). Everything in LDS.
__global__ __launch_bounds__(256) void k_mlp(
    const int*   __restrict__ gidx,
    const float* __restrict__ mxr, const float* __restrict__ mxt,
    const float* __restrict__ ln_g, const float* __restrict__ ln_b,
    const float* __restrict__ W1,  const float* __restrict__ b1,
    const float* __restrict__ W2,  const float* __restrict__ b2,
    float* __restrict__ grgb, float* __restrict__ gtir)
{
    __shared__ float v[2 * SS];     // scattered vector, then normalized vector
    __shared__ float hs[SS];        // hidden relu
    __shared__ float gs[2 * SS];    // sigmoid gates
    __shared__ float red[8];

    const int bh = blockIdx.x;          // 0..383
    const int b  = bh / HN;
    const int t  = threadIdx.x;         // 0..255

    const int sidx = gidx[b * SS + t];  // per-batch permutation entry

    v[t] = 0.f; v[t + SS] = 0.f;
    __syncthreads();
    v[sidx]      = mxr[bh * N1 + t];
    v[sidx + SS] = mxt[bh * N1 + t];
    __syncthreads();

    // LayerNorm over 512
    float x0 = v[t], x1 = v[t + SS];
    float s  = x0 + x1;
    float sq = x0 * x0 + x1 * x1;
#pragma unroll
    for (int off = 32; off; off >>= 1) {
        s  += __shfl_xor(s, off);
        sq += __shfl_xor(sq, off);
    }
    int wv = t >> 6;
    if ((t & 63) == 0) { red[wv] = s; red[4 + wv] = sq; }
    __syncthreads();
    s  = red[0] + red[1] + red[2] + red[3];
    sq = red[4] + red[5] + red[6] + red[7];
    const float mu   = s * (1.f / 512.f);
    const float var  = sq * (1.f / 512.f) - mu * mu;
    const float rstd = rsqrtf(var + 1e-5f);
    v[t]      = (x0 - mu) * rstd * ln_g[t]      + ln_b[t];
    v[t + SS] = (x1 - mu) * rstd * ln_g[t + SS] + ln_b[t + SS];
    __syncthreads();

    // h[t] = relu(sum_e v[e] * W1[e,t] + b1[t]);  W1 is [512,256] row-major
    float acc = b1[t];
#pragma unroll 8
    for (int e = 0; e < 2 * SS; ++e) acc = fmaf(v[e], W1[e * SS + t], acc);
    hs[t] = fmaxf(acc, 0.f);
    __syncthreads();

    // g[t], g[t+256] = sigmoid(sum_f hs[f] * W2[f, .] + b2);  W2 is [256,512]
    float a0 = b2[t], a1 = b2[t + SS];
#pragma unroll 8
    for (int f = 0; f < SS; ++f) {
        float hv = hs[f];
        a0 = fmaf(hv, W2[f * 2 * SS + t],      a0);
        a1 = fmaf(hv, W2[f * 2 * SS + t + SS], a1);
    }
    gs[t]      = 1.f / (1.f + expf(-a0));
    gs[t + SS] = 1.f / (1.f + expf(-a1));
    __syncthreads();

    // pre-gather gates back to (b,h,n1) order
    grgb[bh * N1 + t] = gs[sidx];
    gtir[bh * N1 + t] = gs[sidx + SS];
}

// ---------------- Kernel 3: modulate (pure streaming, float4) ---------------
// d_out = [tir_col | rgb_col], each ROWS*N2 floats.
__global__ __launch_bounds__(256) void k_mod(
    const float* __restrict__ rgb, const float* __restrict__ tir,
    const float* __restrict__ grgb, const float* __restrict__ gtir,
    float4* __restrict__ out)
{
    int i = blockIdx.x * 256 + threadIdx.x;          // 0 .. 2*N4PT-1
    int isRgb = i >= N4PT;                           // second half = rgb output
    int j = isRgb ? i - N4PT : i;
    int row = j / 80;                                // N2/4 = 80 float4 per row
    const float4* src = (const float4*)(isRgb ? rgb : tir);
    float gate = isRgb ? grgb[row] : gtir[row];
    float4 a = src[j];
    float4 o;
    o.x = gate * a.x; o.y = gate * a.y; o.z = gate * a.z; o.w = gate * a.w;
    out[i] = o;
}

extern "C" void kernel_launch(void* const* d_in, const int* in_sizes, int n_in,
                              void* d_out, int out_size, void* d_ws, size_t ws_size,
                              hipStream_t stream)
{
    const float* attn_rgb = (const float*)d_in[0];
    const float* attn_tir = (const float*)d_in[1];
    const int*   gidx     = (const int*)  d_in[2];
    const float* ln_g     = (const float*)d_in[3];
    const float* ln_b     = (const float*)d_in[4];
    const float* W1       = (const float*)d_in[5];
    const float* b1       = (const float*)d_in[6];
    const float* W2       = (const float*)d_in[7];
    const float* b2       = (const float*)d_in[8];
    float* out = (float*)d_out;

    float* ws   = (float*)d_ws;
    float* mxr  = ws;                  // [BH*N1]
    float* mxt  = mxr + ROWS;          // [BH*N1]
    float* grgb = mxt + ROWS;          // [BH*N1]
    float* gtir = grgb + ROWS;         // [BH*N1]

    // K1: 2*ROWS waves, 4 waves per 256-thread block
    int k1_blocks = (2 * ROWS) / 4;    // 49152
    k_rowmax<<<k1_blocks, 256, 0, stream>>>(attn_rgb, attn_tir, mxr, mxt);

    // K2: one block per (b,h)
    k_mlp<<<BH, 256, 0, stream>>>(gidx, mxr, mxt, ln_g, ln_b, W1, b1, W2, b2,
                                  grgb, gtir);

    // K3: 2*N4PT float4 elements
    int k3_blocks = (2 * N4PT) / 256;  // 61440
    k_mod<<<k3_blocks, 256, 0, stream>>>(attn_rgb, attn_tir, grgb, gtir,
                                         (float4*)d_out);
}

// Round 2
// 161.378 us; speedup vs baseline: 1.1214x; 1.1214x over previous
//
#include <hip/hip_runtime.h>
#include <hip/hip_bf16.h>
#include <math.h>

// Problem constants
#define BB   32
#define HN   12
#define N1   256
#define N2   320
#define SS   256
#define BH   (BB*HN)            // 384
#define ROWS (BH*N1)            // 98304 rows per tensor
#define N4PT ((BH*N1*N2)/4)     // float4 count per tensor = 7,864,320

typedef float v4f __attribute__((ext_vector_type(4)));

// ---------------- Kernel 1: row max over N2 for both tensors ----------------
// one wave (64 lanes) per row; 80 float4 per row = 64 lanes + 16 predicated.
__global__ __launch_bounds__(256) void k_rowmax(
    const float* __restrict__ rgb, const float* __restrict__ tir,
    float* __restrict__ mxr, float* __restrict__ mxt)
{
    int wid  = (blockIdx.x * 256 + threadIdx.x) >> 6;   // global wave id
    int lane = threadIdx.x & 63;
    int isTir = wid >= ROWS;
    int row  = isTir ? wid - ROWS : wid;
    const v4f* p = (const v4f*)((isTir ? tir : rgb) + (size_t)row * N2);
    v4f a = p[lane];
    float m = fmaxf(fmaxf(a.x, a.y), fmaxf(a.z, a.w));
    if (lane < 16) {
        v4f b = p[64 + lane];
        m = fmaxf(m, fmaxf(fmaxf(b.x, b.y), fmaxf(b.z, b.w)));
    }
#pragma unroll
    for (int off = 32; off; off >>= 1) m = fmaxf(m, __shfl_xor(m, off));
    if (lane == 0) (isTir ? mxt : mxr)[row] = m;
}

// ---------------- Kernel 2: scatter -> LayerNorm -> MLP -> gather gates -----
// one block (256 threads) per FOUR (b,h) rows: weights read once per 4 rows,
// 4 independent fma chains for ILP.
__global__ __launch_bounds__(256) void k_mlp(
    const int*   __restrict__ gidx,
    const float* __restrict__ mxr, const float* __restrict__ mxt,
    const float* __restrict__ ln_g, const float* __restrict__ ln_b,
    const float* __restrict__ W1,  const float* __restrict__ b1,
    const float* __restrict__ W2,  const float* __restrict__ b2,
    float* __restrict__ grgb, float* __restrict__ gtir)
{
    __shared__ float v[4][2 * SS];   // scattered -> normalized vectors
    __shared__ float hs[4][SS];      // hidden relu
    __shared__ float gs[4][2 * SS];  // sigmoid gates

    const int t   = threadIdx.x;     // 0..255
    const int bh0 = blockIdx.x * 4;

#pragma unroll
    for (int r = 0; r < 4; ++r) { v[r][t] = 0.f; v[r][t + SS] = 0.f; }
    __syncthreads();
#pragma unroll
    for (int r = 0; r < 4; ++r) {
        int bh   = bh0 + r;
        int b    = bh / HN;
        int sidx = gidx[b * SS + t];
        v[r][sidx]      = mxr[bh * N1 + t];
        v[r][sidx + SS] = mxt[bh * N1 + t];
    }
    __syncthreads();

    // LayerNorm over 512: wave w handles row w (8 elements per lane)
    {
        int w = t >> 6, l = t & 63;
        float xs[8];
        float s = 0.f, sq = 0.f;
#pragma unroll
        for (int k = 0; k < 8; ++k) {
            xs[k] = v[w][l + 64 * k];
            s += xs[k]; sq = fmaf(xs[k], xs[k], sq);
        }
#pragma unroll
        for (int off = 32; off; off >>= 1) {
            s  += __shfl_xor(s, off);
            sq += __shfl_xor(sq, off);
        }
        float mu   = s * (1.f / 512.f);
        float var  = sq * (1.f / 512.f) - mu * mu;
        float rstd = rsqrtf(var + 1e-5f);
#pragma unroll
        for (int k = 0; k < 8; ++k) {
            int i = l + 64 * k;
            v[w][i] = (xs[k] - mu) * rstd * ln_g[i] + ln_b[i];
        }
    }
    __syncthreads();

    // GEMM1: hs[r][t] = relu(sum_e v[r][e] * W1[e*256+t] + b1[t])
    {
        float acc0 = b1[t], acc1 = acc0, acc2 = acc0, acc3 = acc0;
#pragma unroll 4
        for (int e4 = 0; e4 < 128; ++e4) {
            v4f v0 = *(const v4f*)&v[0][e4 * 4];
            v4f v1 = *(const v4f*)&v[1][e4 * 4];
            v4f v2 = *(const v4f*)&v[2][e4 * 4];
            v4f v3 = *(const v4f*)&v[3][e4 * 4];
            float w0 = W1[(e4 * 4 + 0) * SS + t];
            float w1 = W1[(e4 * 4 + 1) * SS + t];
            float w2 = W1[(e4 * 4 + 2) * SS + t];
            float w3 = W1[(e4 * 4 + 3) * SS + t];
            acc0 = fmaf(v0.x, w0, acc0); acc0 = fmaf(v0.y, w1, acc0);
            acc0 = fmaf(v0.z, w2, acc0); acc0 = fmaf(v0.w, w3, acc0);
            acc1 = fmaf(v1.x, w0, acc1); acc1 = fmaf(v1.y, w1, acc1);
            acc1 = fmaf(v1.z, w2, acc1); acc1 = fmaf(v1.w, w3, acc1);
            acc2 = fmaf(v2.x, w0, acc2); acc2 = fmaf(v2.y, w1, acc2);
            acc2 = fmaf(v2.z, w2, acc2); acc2 = fmaf(v2.w, w3, acc2);
            acc3 = fmaf(v3.x, w0, acc3); acc3 = fmaf(v3.y, w1, acc3);
            acc3 = fmaf(v3.z, w2, acc3); acc3 = fmaf(v3.w, w3, acc3);
        }
        hs[0][t] = fmaxf(acc0, 0.f);
        hs[1][t] = fmaxf(acc1, 0.f);
        hs[2][t] = fmaxf(acc2, 0.f);
        hs[3][t] = fmaxf(acc3, 0.f);
    }
    __syncthreads();

    // GEMM2: gs[r][t], gs[r][t+256] = sigmoid(sum_f hs[r][f] * W2[f*512 + .] + b2)
    {
        float alo0 = b2[t],      alo1 = alo0, alo2 = alo0, alo3 = alo0;
        float ahi0 = b2[t + SS], ahi1 = ahi0, ahi2 = ahi0, ahi3 = ahi0;
#pragma unroll 4
        for (int f4 = 0; f4 < 64; ++f4) {
            v4f h0 = *(const v4f*)&hs[0][f4 * 4];
            v4f h1 = *(const v4f*)&hs[1][f4 * 4];
            v4f h2 = *(const v4f*)&hs[2][f4 * 4];
            v4f h3 = *(const v4f*)&hs[3][f4 * 4];
#pragma unroll
            for (int q = 0; q < 4; ++q) {
                int f = f4 * 4 + q;
                float wlo = W2[f * 2 * SS + t];
                float whi = W2[f * 2 * SS + t + SS];
                float e0 = (q == 0) ? h0.x : (q == 1) ? h0.y : (q == 2) ? h0.z : h0.w;
                float e1 = (q == 0) ? h1.x : (q == 1) ? h1.y : (q == 2) ? h1.z : h1.w;
                float e2 = (q == 0) ? h2.x : (q == 1) ? h2.y : (q == 2) ? h2.z : h2.w;
                float e3 = (q == 0) ? h3.x : (q == 1) ? h3.y : (q == 2) ? h3.z : h3.w;
                alo0 = fmaf(e0, wlo, alo0); ahi0 = fmaf(e0, whi, ahi0);
                alo1 = fmaf(e1, wlo, alo1); ahi1 = fmaf(e1, whi, ahi1);
                alo2 = fmaf(e2, wlo, alo2); ahi2 = fmaf(e2, whi, ahi2);
                alo3 = fmaf(e3, wlo, alo3); ahi3 = fmaf(e3, whi, ahi3);
            }
        }
        gs[0][t] = 1.f / (1.f + expf(-alo0)); gs[0][t + SS] = 1.f / (1.f + expf(-ahi0));
        gs[1][t] = 1.f / (1.f + expf(-alo1)); gs[1][t + SS] = 1.f / (1.f + expf(-ahi1));
        gs[2][t] = 1.f / (1.f + expf(-alo2)); gs[2][t + SS] = 1.f / (1.f + expf(-ahi2));
        gs[3][t] = 1.f / (1.f + expf(-alo3)); gs[3][t + SS] = 1.f / (1.f + expf(-ahi3));
    }
    __syncthreads();

    // pre-gather gates back to (b,h,n1) order
#pragma unroll
    for (int r = 0; r < 4; ++r) {
        int bh   = bh0 + r;
        int b    = bh / HN;
        int sidx = gidx[b * SS + t];
        grgb[bh * N1 + t] = gs[r][sidx];
        gtir[bh * N1 + t] = gs[r][sidx + SS];
    }
}

// ---------------- Kernel 3: modulate (streaming, float4, NT stores) ---------
// d_out = [tir_col | rgb_col]. Inputs should be L3-resident from k1; NT
// stores keep the output from evicting them.
__global__ __launch_bounds__(256) void k_mod(
    const float* __restrict__ rgb, const float* __restrict__ tir,
    const float* __restrict__ grgb, const float* __restrict__ gtir,
    v4f* __restrict__ out)
{
    int i = blockIdx.x * 256 + threadIdx.x;          // 0 .. 2*N4PT-1
    int isRgb = i >= N4PT;                           // second half = rgb output
    int j = isRgb ? i - N4PT : i;
    int row = j / 80;                                // N2/4 = 80 float4 per row
    const v4f* src = (const v4f*)(isRgb ? rgb : tir);
    float gate = isRgb ? grgb[row] : gtir[row];
    v4f a = src[j];
    v4f o = a * gate;
    __builtin_nontemporal_store(o, &out[i]);
}

extern "C" void kernel_launch(void* const* d_in, const int* in_sizes, int n_in,
                              void* d_out, int out_size, void* d_ws, size_t ws_size,
                              hipStream_t stream)
{
    const float* attn_rgb = (const float*)d_in[0];
    const float* attn_tir = (const float*)d_in[1];
    const int*   gidx     = (const int*)  d_in[2];
    const float* ln_g     = (const float*)d_in[3];
    const float* ln_b     = (const float*)d_in[4];
    const float* W1       = (const float*)d_in[5];
    const float* b1       = (const float*)d_in[6];
    const float* W2       = (const float*)d_in[7];
    const float* b2       = (const float*)d_in[8];

    float* ws   = (float*)d_ws;
    float* mxr  = ws;                  // [BH*N1]
    float* mxt  = mxr + ROWS;          // [BH*N1]
    float* grgb = mxt + ROWS;          // [BH*N1]
    float* gtir = grgb + ROWS;         // [BH*N1]

    // K1: 2*ROWS waves, 4 waves per 256-thread block
    int k1_blocks = (2 * ROWS) / 4;    // 49152
    k_rowmax<<<k1_blocks, 256, 0, stream>>>(attn_rgb, attn_tir, mxr, mxt);

    // K2: one block per 4 (b,h) rows
    k_mlp<<<BH / 4, 256, 0, stream>>>(gidx, mxr, mxt, ln_g, ln_b, W1, b1, W2, b2,
                                      grgb, gtir);

    // K3: 2*N4PT float4 elements
    int k3_blocks = (2 * N4PT) / 256;  // 61440
    k_mod<<<k3_blocks, 256, 0, stream>>>(attn_rgb, attn_tir, grgb, gtir,
                                         (v4f*)d_out);
}